// Round 5
// baseline (961.116 us; speedup 1.0000x reference)
//
#include <hip/hip_runtime.h>
#include <hip/hip_bf16.h>

#define NN_ 30000
#define NE_ 480000
#define DIM 128
#define EINF 16
#define EOUTF 16
#define NG 64
#define RSQRT_DH 0.17677669529663687f

// ---------------- workspace layout (32-bit word offsets) ----------------
// total 14,075,736 words = 56.3 MB
#define W_DEG     0
#define W_CUR     30000
#define W_GSUM1   60000
#define W_GSQ1    68192
#define W_GSUM2   76384
#define W_GSQ2    84576
#define W_ZEND    92768
#define W_OFF     92768
#define W_BSUM    122772
#define W_GSTART  122900
#define W_EID     122968
#define W_SCORES  602968
#define W_A       2522968
#define W_B       6362968
#define W_C       10202968
#define W_WGC     14042968

// ---------------- GEMM building blocks (K=128, 32-row tile, 256 thr) ----
static __device__ __forceinline__ void stage32(const float* __restrict__ X,
                                               float* xsb, int row0, int tid) {
#pragma unroll
  for (int t = 0; t < 4; ++t) {
    int idx = tid + t * 256;
    int r = idx >> 5, c4 = (idx & 31) * 4;
    int row = row0 + r;
    float4 v; v.x = v.y = v.z = v.w = 0.f;
    if (row < NN_) v = *(const float4*)&X[(size_t)row * DIM + c4];
    *(float4*)&xsb[r * DIM + c4] = v;
  }
}

static __device__ __forceinline__ void mm_k128(const float* xsb, int ld,
                                               const float* __restrict__ W,
                                               float acc[4][4], int tid) {
  int cg = tid & 31, rg = tid >> 5;
  int c0 = cg * 4, r0 = rg * 4;
  for (int k = 0; k < 128; k += 4) {
    float4 w0 = *(const float4*)&W[(size_t)(k + 0) * DIM + c0];
    float4 w1 = *(const float4*)&W[(size_t)(k + 1) * DIM + c0];
    float4 w2 = *(const float4*)&W[(size_t)(k + 2) * DIM + c0];
    float4 w3 = *(const float4*)&W[(size_t)(k + 3) * DIM + c0];
#pragma unroll
    for (int u = 0; u < 4; ++u) {
      float4 xv = *(const float4*)&xsb[(r0 + u) * ld + k];
      acc[u][0] += xv.x * w0.x + xv.y * w1.x + xv.z * w2.x + xv.w * w3.x;
      acc[u][1] += xv.x * w0.y + xv.y * w1.y + xv.z * w2.y + xv.w * w3.y;
      acc[u][2] += xv.x * w0.z + xv.y * w1.z + xv.z * w2.z + xv.w * w3.z;
      acc[u][3] += xv.x * w0.w + xv.y * w1.w + xv.z * w2.w + xv.w * w3.w;
    }
  }
}

static __device__ __forceinline__ void epi_store(float acc[4][4],
    const float* __restrict__ bias, float* __restrict__ Y,
    int row0, int tid, int act) {
  int cg = tid & 31, rg = tid >> 5;
  int c0 = cg * 4, r0 = rg * 4;
  float4 bv = *(const float4*)&bias[c0];
#pragma unroll
  for (int u = 0; u < 4; ++u) {
    int row = row0 + r0 + u;
    if (row >= NN_) continue;
    float o0 = acc[u][0] + bv.x, o1 = acc[u][1] + bv.y;
    float o2 = acc[u][2] + bv.z, o3 = acc[u][3] + bv.w;
    if (act == 1) {
      o0 = o0 > 0.f ? o0 : 0.01f * o0;
      o1 = o1 > 0.f ? o1 : 0.01f * o1;
      o2 = o2 > 0.f ? o2 : 0.01f * o2;
      o3 = o3 > 0.f ? o3 : 0.01f * o3;
    }
    float4 ov; ov.x = o0; ov.y = o1; ov.z = o2; ov.w = o3;
    *(float4*)&Y[(size_t)row * DIM + c0] = ov;
  }
}

// ---------------- small utility kernels ----------------
__global__ void zero_kernel(int* p, int n) {
  int i = blockIdx.x * 256 + threadIdx.x;
  if (i < n) p[i] = 0;
}

__global__ void gstart_kernel(const int* __restrict__ batch, int* __restrict__ gstart) {
  int g = threadIdx.x;
  if (g > NG) return;
  int lo = 0, hi = NN_;
  while (lo < hi) { int mid = (lo + hi) >> 1; if (batch[mid] < g) lo = mid + 1; else hi = mid; }
  gstart[g] = lo;
}

__global__ void prep_wg_kernel(const float* __restrict__ Wg, float* __restrict__ Wgc) {
  int idx = blockIdx.x * 256 + threadIdx.x;  // 256*128
  int k = idx >> 7, c = idx & 127;
  float v;
  if (k < 128) v = Wg[(size_t)k * DIM + c] + Wg[(size_t)(256 + k) * DIM + c];
  else { int kk = k - 128; v = Wg[(size_t)(128 + kk) * DIM + c] - Wg[(size_t)(256 + kk) * DIM + c]; }
  Wgc[idx] = v;
}

// ---------------- node projections: src,dst,value ----------------
__global__ void __launch_bounds__(256) proj_kernel(
    const float* __restrict__ node,
    const float* __restrict__ Ws, const float* __restrict__ bs,
    const float* __restrict__ Wd, const float* __restrict__ bd,
    const float* __restrict__ Wv, const float* __restrict__ bv,
    float* __restrict__ srcp, float* __restrict__ dstp, float* __restrict__ valp) {
  __shared__ __align__(16) float xs[32 * DIM];
  int tid = threadIdx.x, row0 = blockIdx.x * 32;
  stage32(node, xs, row0, tid);
  __syncthreads();
  const float* Wt[3] = {Ws, Wd, Wv};
  const float* Bt[3] = {bs, bd, bv};
  float* Yt[3] = {srcp, dstp, valp};
#pragma unroll
  for (int w3 = 0; w3 < 3; ++w3) {
    float acc[4][4] = {};
    mm_k128(xs, DIM, Wt[w3], acc, tid);
    epi_store(acc, Bt[w3], Yt[w3], row0, tid, 0);
  }
}

// ---------------- generic node GEMM (in-place safe: own tile staged) ---
__global__ void __launch_bounds__(256) gemm128_kernel(
    const float* __restrict__ X, const float* __restrict__ W,
    const float* __restrict__ bias, float* __restrict__ Y, int act) {
  __shared__ __align__(16) float xs[32 * DIM];
  int tid = threadIdx.x, row0 = blockIdx.x * 32;
  stage32(X, xs, row0, tid);
  __syncthreads();
  float acc[4][4] = {};
  mm_k128(xs, DIM, W, acc, tid);
  epi_store(acc, bias, Y, row0, tid, act);
}

// ---------------- gate: g = sigmoid([nn,x,nn-x]@Wg+bg); x1 = g*nn + x ----
__global__ void __launch_bounds__(256) gate_kernel(
    const float* __restrict__ NNb, const float* __restrict__ NODE,
    const float* __restrict__ Wgc, const float* __restrict__ bg,
    float* __restrict__ G, float* __restrict__ X1) {
  __shared__ __align__(16) float xs0[32 * DIM];
  __shared__ __align__(16) float xs1[32 * DIM];
  int tid = threadIdx.x, row0 = blockIdx.x * 32;
  stage32(NNb, xs0, row0, tid);
  stage32(NODE, xs1, row0, tid);
  __syncthreads();
  float acc[4][4] = {};
  mm_k128(xs0, DIM, Wgc, acc, tid);
  mm_k128(xs1, DIM, Wgc + 128 * DIM, acc, tid);
  int cg = tid & 31, rg = tid >> 5, c0 = cg * 4, r0 = rg * 4;
  float4 bv = *(const float4*)&bg[c0];
#pragma unroll
  for (int u = 0; u < 4; ++u) {
    int row = row0 + r0 + u;
    if (row >= NN_) continue;
    float z0 = acc[u][0] + bv.x, z1 = acc[u][1] + bv.y;
    float z2 = acc[u][2] + bv.z, z3 = acc[u][3] + bv.w;
    float g0 = 1.f / (1.f + __expf(-z0));
    float g1 = 1.f / (1.f + __expf(-z1));
    float g2 = 1.f / (1.f + __expf(-z2));
    float g3 = 1.f / (1.f + __expf(-z3));
    float4 nn4 = *(const float4*)&xs0[(r0 + u) * DIM + c0];
    float4 nd4 = *(const float4*)&xs1[(r0 + u) * DIM + c0];
    float4 gv; gv.x = g0; gv.y = g1; gv.z = g2; gv.w = g3;
    float4 xv; xv.x = g0 * nn4.x + nd4.x; xv.y = g1 * nn4.y + nd4.y;
    xv.z = g2 * nn4.z + nd4.z; xv.w = g3 * nn4.w + nd4.w;
    *(float4*)&G[(size_t)row * DIM + c0] = gv;
    *(float4*)&X1[(size_t)row * DIM + c0] = xv;
  }
}

// ---------------- fx2 + residual gate epilogue: x2 = g*fx + n1 ----------
__global__ void __launch_bounds__(256) fx2_kernel(
    const float* __restrict__ T, const float* __restrict__ Wf2,
    const float* __restrict__ bf2, const float* __restrict__ G,
    const float* __restrict__ N1, float* __restrict__ X2) {
  __shared__ __align__(16) float xs[32 * DIM];
  int tid = threadIdx.x, row0 = blockIdx.x * 32;
  stage32(T, xs, row0, tid);
  __syncthreads();
  float acc[4][4] = {};
  mm_k128(xs, DIM, Wf2, acc, tid);
  int cg = tid & 31, rg = tid >> 5, c0 = cg * 4, r0 = rg * 4;
  float4 bv = *(const float4*)&bf2[c0];
#pragma unroll
  for (int u = 0; u < 4; ++u) {
    int row = row0 + r0 + u;
    if (row >= NN_) continue;
    float4 gv = *(const float4*)&G[(size_t)row * DIM + c0];
    float4 nv = *(const float4*)&N1[(size_t)row * DIM + c0];
    float4 ov;
    ov.x = gv.x * (acc[u][0] + bv.x) + nv.x;
    ov.y = gv.y * (acc[u][1] + bv.y) + nv.y;
    ov.z = gv.z * (acc[u][2] + bv.z) + nv.z;
    ov.w = gv.w * (acc[u][3] + bv.w) + nv.w;
    *(float4*)&X2[(size_t)row * DIM + c0] = ov;
  }
}

// ---------------- the big fused edge kernel ----------------
__global__ void __launch_bounds__(256) edge_kernel(
    const float* __restrict__ edgef, const float* __restrict__ coords,
    const int* __restrict__ EI,
    const float* __restrict__ We1, const float* __restrict__ be1,
    const float* __restrict__ We2, const float* __restrict__ be2,
    const float* __restrict__ Wue, const float* __restrict__ bue,
    const float* __restrict__ srcp, const float* __restrict__ dstp,
    float* __restrict__ scores, int* __restrict__ deg,
    float* __restrict__ outE) {
  __shared__ __align__(16) float xs[32 * 20];      // [32][20] padded edge inputs
  __shared__ __align__(16) float Wp[20 * DIM];     // padded We1
  __shared__ __align__(16) float hs[32 * 132];     // h, then er (pad 132)
  __shared__ __align__(16) float wue_s[DIM * EOUTF];
  __shared__ float bue_s[EOUTF];
  __shared__ int ii[32], jj[32];

  int tid = threadIdx.x;
  int e0 = blockIdx.x * 32;

  if (tid < 128) {                      // stage 32x16 edge feats as float4
    int r = tid >> 2, c4 = (tid & 3) * 4;
    *(float4*)&xs[r * 20 + c4] = *(const float4*)&edgef[(size_t)(e0 + r) * EINF + c4];
  }
  if (tid < 32) {
    int e = e0 + tid;
    int i = EI[e], j = EI[NE_ + e];
    ii[tid] = i; jj[tid] = j;
    float dx = coords[i * 3 + 0] - coords[j * 3 + 0];
    float dy = coords[i * 3 + 1] - coords[j * 3 + 1];
    float dz = coords[i * 3 + 2] - coords[j * 3 + 2];
    float dist = sqrtf(dx * dx + dy * dy + dz * dz + 1e-12f) * 0.1f;
    xs[tid * 20 + 16] = dist;
    xs[tid * 20 + 17] = 0.f; xs[tid * 20 + 18] = 0.f; xs[tid * 20 + 19] = 0.f;
    atomicAdd(&deg[i], 1);
  }
  for (int idx = tid; idx < 20 * DIM; idx += 256) {
    int k = idx >> 7, c = idx & 127;
    Wp[idx] = (k < 17) ? We1[(size_t)k * DIM + c] : 0.f;
  }
  for (int idx = tid; idx < DIM * EOUTF; idx += 256) wue_s[idx] = Wue[idx];
  if (tid < EOUTF) bue_s[tid] = bue[tid];
  __syncthreads();

  int cg = tid & 31, rg = tid >> 5, c0 = cg * 4, r0 = rg * 4;

  // h = leaky(x @ We1 + be1), K = 20 (padded)
  float acc[4][4] = {};
  for (int k = 0; k < 20; k += 4) {
    float4 w0 = *(const float4*)&Wp[(k + 0) * DIM + c0];
    float4 w1 = *(const float4*)&Wp[(k + 1) * DIM + c0];
    float4 w2 = *(const float4*)&Wp[(k + 2) * DIM + c0];
    float4 w3 = *(const float4*)&Wp[(k + 3) * DIM + c0];
#pragma unroll
    for (int u = 0; u < 4; ++u) {
      float4 xv = *(const float4*)&xs[(r0 + u) * 20 + k];
      acc[u][0] += xv.x * w0.x + xv.y * w1.x + xv.z * w2.x + xv.w * w3.x;
      acc[u][1] += xv.x * w0.y + xv.y * w1.y + xv.z * w2.y + xv.w * w3.y;
      acc[u][2] += xv.x * w0.z + xv.y * w1.z + xv.z * w2.z + xv.w * w3.z;
      acc[u][3] += xv.x * w0.w + xv.y * w1.w + xv.z * w2.w + xv.w * w3.w;
    }
  }
  float4 b1 = *(const float4*)&be1[c0];
#pragma unroll
  for (int u = 0; u < 4; ++u) {
    float h0 = acc[u][0] + b1.x, h1 = acc[u][1] + b1.y;
    float h2 = acc[u][2] + b1.z, h3 = acc[u][3] + b1.w;
    h0 = h0 > 0.f ? h0 : 0.01f * h0; h1 = h1 > 0.f ? h1 : 0.01f * h1;
    h2 = h2 > 0.f ? h2 : 0.01f * h2; h3 = h3 > 0.f ? h3 : 0.01f * h3;
    float4 hv; hv.x = h0; hv.y = h1; hv.z = h2; hv.w = h3;
    *(float4*)&hs[(r0 + u) * 132 + c0] = hv;
  }
  __syncthreads();

  // e2 = h @ We2 + be2 ; er = dst_i * src_j * e2 / sqrt(DH)
  float a2[4][4] = {};
  mm_k128(hs, 132, We2, a2, tid);
  float4 b2 = *(const float4*)&be2[c0];
  float er[4][4];
  float p[4];
#pragma unroll
  for (int u = 0; u < 4; ++u) {
    int iu = ii[r0 + u], ju = jj[r0 + u];
    float4 sv = *(const float4*)&srcp[(size_t)ju * DIM + c0];
    float4 dv = *(const float4*)&dstp[(size_t)iu * DIM + c0];
    er[u][0] = dv.x * sv.x * (a2[u][0] + b2.x) * RSQRT_DH;
    er[u][1] = dv.y * sv.y * (a2[u][1] + b2.y) * RSQRT_DH;
    er[u][2] = dv.z * sv.z * (a2[u][2] + b2.z) * RSQRT_DH;
    er[u][3] = dv.w * sv.w * (a2[u][3] + b2.w) * RSQRT_DH;
    p[u] = fabsf(er[u][0]) + fabsf(er[u][1]) + fabsf(er[u][2]) + fabsf(er[u][3]);
  }
  __syncthreads();   // everyone finished reading hs (h)
#pragma unroll
  for (int u = 0; u < 4; ++u) {
    float4 t; t.x = er[u][0]; t.y = er[u][1]; t.z = er[u][2]; t.w = er[u][3];
    *(float4*)&hs[(r0 + u) * 132 + c0] = t;
  }
  // scores: reduce |er| over the 8 col-groups of each head
#pragma unroll
  for (int m = 1; m < 8; m <<= 1) {
#pragma unroll
    for (int u = 0; u < 4; ++u) p[u] += __shfl_xor(p[u], m);
  }
  if ((cg & 7) == 0) {
    int head = cg >> 3;
#pragma unroll
    for (int u = 0; u < 4; ++u)
      scores[(size_t)(e0 + r0 + u) * 4 + head] = p[u];
  }
  __syncthreads();   // er fully in LDS

  // edge_new = er @ Wue + bue  -> f32 out
  int el = tid >> 3, oc2 = (tid & 7) * 2;
  float a0 = 0.f, a1 = 0.f;
  for (int k = 0; k < DIM; ++k) {
    float hv = hs[el * 132 + k];
    float2 wv = *(const float2*)&wue_s[k * EOUTF + oc2];
    a0 += hv * wv.x; a1 += hv * wv.y;
  }
  size_t ob = (size_t)(e0 + el) * EOUTF + oc2;
  float2 o2; o2.x = a0 + bue_s[oc2]; o2.y = a1 + bue_s[oc2 + 1];
  *(float2*)&outE[ob] = o2;
}

// ---------------- CSR build ----------------
__global__ void scanA_kernel(const int* __restrict__ deg, int* __restrict__ off,
                             int* __restrict__ bsum) {
  __shared__ int buf[256];
  int tid = threadIdx.x;
  int i = blockIdx.x * 256 + tid;
  int v = (i < NN_) ? deg[i] : 0;
  buf[tid] = v;
  __syncthreads();
  for (int s = 1; s < 256; s <<= 1) {
    int t = (tid >= s) ? buf[tid - s] : 0;
    __syncthreads();
    buf[tid] += t;
    __syncthreads();
  }
  if (i < NN_) off[i] = buf[tid] - v;
  if (tid == 255) bsum[blockIdx.x] = buf[255];
}

__global__ void scanB_kernel(int* __restrict__ bsum) {
  const int NBLK = (NN_ + 255) / 256;
  __shared__ int buf[128];
  int tid = threadIdx.x;
  int v = (tid < NBLK) ? bsum[tid] : 0;
  buf[tid] = v;
  __syncthreads();
  for (int s = 1; s < 128; s <<= 1) {
    int t = (tid >= s) ? buf[tid - s] : 0;
    __syncthreads();
    buf[tid] += t;
    __syncthreads();
  }
  if (tid < NBLK) bsum[tid] = buf[tid] - v;
}

__global__ void scanC_kernel(int* __restrict__ off, const int* __restrict__ bsum) {
  int i = blockIdx.x * 256 + threadIdx.x;
  if (i < NN_) off[i] += bsum[i >> 8];
  if (i == 0) off[NN_] = NE_;
}

__global__ void fill_kernel(const int* __restrict__ EI, const int* __restrict__ off,
                            int* __restrict__ cur, int* __restrict__ eidb) {
  int e = blockIdx.x * 256 + threadIdx.x;
  if (e >= NE_) return;
  int i = EI[e];
  int p = atomicAdd(&cur[i], 1);
  eidb[off[i] + p] = e;
}

// ---------------- per-node softmax + aggregation (gather, no atomics) ---
__global__ void __launch_bounds__(256) agg_kernel(
    const float* __restrict__ valp, const float* __restrict__ scores,
    const int* __restrict__ off, const int* __restrict__ eidb,
    const int* __restrict__ EI, float* __restrict__ agg) {
  int n = blockIdx.x * 4 + (threadIdx.x >> 6);
  int lane = threadIdx.x & 63;
  if (n >= NN_) return;
  int s = off[n], e_end = off[n + 1];

  float m0 = -1e30f, m1 = -1e30f, m2 = -1e30f, m3 = -1e30f;
  for (int p = s + lane; p < e_end; p += 64) {
    int e = eidb[p];
    float4 sc = *(const float4*)&scores[(size_t)e * 4];
    m0 = fmaxf(m0, sc.x); m1 = fmaxf(m1, sc.y);
    m2 = fmaxf(m2, sc.z); m3 = fmaxf(m3, sc.w);
  }
#pragma unroll
  for (int d = 1; d < 64; d <<= 1) {
    m0 = fmaxf(m0, __shfl_xor(m0, d)); m1 = fmaxf(m1, __shfl_xor(m1, d));
    m2 = fmaxf(m2, __shfl_xor(m2, d)); m3 = fmaxf(m3, __shfl_xor(m3, d));
  }
  int h0 = lane >> 5;               // head for dim=lane (0/1); dim=lane+64 -> head 2+h0
  float mh0 = h0 ? m1 : m0;
  float mh1 = h0 ? m3 : m2;

  float acc0 = 0.f, acc1 = 0.f, den0 = 0.f, den1 = 0.f;
  for (int p = s; p < e_end; ++p) {
    int e = eidb[p];
    int j = EI[NE_ + e];
    float s0 = scores[(size_t)e * 4 + h0];
    float s1 = scores[(size_t)e * 4 + 2 + h0];
    float ex0 = __expf(s0 - mh0), ex1 = __expf(s1 - mh1);
    den0 += ex0; den1 += ex1;
    acc0 += ex0 * valp[(size_t)j * DIM + lane];
    acc1 += ex1 * valp[(size_t)j * DIM + 64 + lane];
  }
  if (e_end > s) {
    agg[(size_t)n * DIM + lane]      = acc0 / den0;
    agg[(size_t)n * DIM + 64 + lane] = acc1 / den1;
  } else {
    agg[(size_t)n * DIM + lane] = 0.f;
    agg[(size_t)n * DIM + 64 + lane] = 0.f;
  }
}

// ---------------- GraphNorm ----------------
__global__ void gn_stats_kernel(const float* __restrict__ X, const int* __restrict__ gstart,
                                float* __restrict__ gsum, float* __restrict__ gsq) {
  int g = blockIdx.x, slice = blockIdx.y;
  int s = gstart[g], e = gstart[g + 1];
  int c = threadIdx.x & 127, half = threadIdx.x >> 7;
  float sm = 0.f, sq = 0.f;
  for (int n = s + slice * 2 + half; n < e; n += 16) {
    float v = X[(size_t)n * DIM + c];
    sm += v; sq += v * v;
  }
  __shared__ float bsm[2][DIM], bsq[2][DIM];
  bsm[half][c] = sm; bsq[half][c] = sq;
  __syncthreads();
  if (half == 0) {
    atomicAdd(&gsum[g * DIM + c], bsm[0][c] + bsm[1][c]);
    atomicAdd(&gsq[g * DIM + c],  bsq[0][c] + bsq[1][c]);
  }
}

__global__ void gn_apply_kernel(const float* __restrict__ X, const int* __restrict__ batch,
    const int* __restrict__ gstart, const float* __restrict__ gsum,
    const float* __restrict__ gsq, const float* __restrict__ w,
    const float* __restrict__ b, const float* __restrict__ a,
    float* __restrict__ Y) {
  int idx = blockIdx.x * 256 + threadIdx.x;
  if (idx >= NN_ * 32) return;
  int n = idx >> 5, c4 = (idx & 31) * 4;
  int g = batch[n];
  float cnt = fmaxf((float)(gstart[g + 1] - gstart[g]), 1.f);
  float inv = 1.f / cnt;
  float4 xv = *(const float4*)&X[(size_t)n * DIM + c4];
  float4 sm = *(const float4*)&gsum[g * DIM + c4];
  float4 sq = *(const float4*)&gsq[g * DIM + c4];
  float4 av = *(const float4*)&a[c4];
  float4 wv = *(const float4*)&w[c4];
  float4 bv = *(const float4*)&b[c4];
  float4 ov;
  {
    float mean = sm.x * inv, msq = sq.x * inv, am = av.x * mean;
    float var = msq - 2.f * am * mean + am * am;
    ov.x = wv.x * (xv.x - am) * rsqrtf(var + 1e-5f) + bv.x;
  }
  {
    float mean = sm.y * inv, msq = sq.y * inv, am = av.y * mean;
    float var = msq - 2.f * am * mean + am * am;
    ov.y = wv.y * (xv.y - am) * rsqrtf(var + 1e-5f) + bv.y;
  }
  {
    float mean = sm.z * inv, msq = sq.z * inv, am = av.z * mean;
    float var = msq - 2.f * am * mean + am * am;
    ov.z = wv.z * (xv.z - am) * rsqrtf(var + 1e-5f) + bv.z;
  }
  {
    float mean = sm.w * inv, msq = sq.w * inv, am = av.w * mean;
    float var = msq - 2.f * am * mean + am * am;
    ov.w = wv.w * (xv.w - am) * rsqrtf(var + 1e-5f) + bv.w;
  }
  *(float4*)&Y[(size_t)n * DIM + c4] = ov;
}

__global__ void coords_kernel(const float* __restrict__ C, float* __restrict__ O) {
  int i = blockIdx.x * 256 + threadIdx.x;
  if (i < NN_ * 3) O[i] = C[i];
}

// ---------------- launcher ----------------
extern "C" void kernel_launch(void* const* d_in, const int* in_sizes, int n_in,
                              void* d_out, int out_size, void* d_ws, size_t ws_size,
                              hipStream_t stream) {
  (void)in_sizes; (void)n_in; (void)out_size; (void)ws_size;
  const float* node  = (const float*)d_in[0];
  const float* edgef = (const float*)d_in[1];
  const float* coords= (const float*)d_in[2];
  const float* Ws  = (const float*)d_in[3];  const float* bs  = (const float*)d_in[4];
  const float* Wd  = (const float*)d_in[5];  const float* bd  = (const float*)d_in[6];
  const float* Wv  = (const float*)d_in[7];  const float* bv  = (const float*)d_in[8];
  const float* We1 = (const float*)d_in[9];  const float* be1 = (const float*)d_in[10];
  const float* We2 = (const float*)d_in[11]; const float* be2 = (const float*)d_in[12];
  const float* Wun = (const float*)d_in[13]; const float* bun = (const float*)d_in[14];
  const float* Wue = (const float*)d_in[15]; const float* bue = (const float*)d_in[16];
  const float* Wg  = (const float*)d_in[17]; const float* bg  = (const float*)d_in[18];
  const float* Wf1 = (const float*)d_in[19]; const float* bf1 = (const float*)d_in[20];
  const float* Wf2 = (const float*)d_in[21]; const float* bf2 = (const float*)d_in[22];
  const float* g1w = (const float*)d_in[23]; const float* g1b = (const float*)d_in[24];
  const float* g1a = (const float*)d_in[25];
  const float* g2w = (const float*)d_in[26]; const float* g2b = (const float*)d_in[27];
  const float* g2a = (const float*)d_in[28];
  const int* EI    = (const int*)d_in[29];
  const int* batch = (const int*)d_in[30];
  float* out = (float*)d_out;               // fp32 output, per reference dtype

  int*   wsi = (int*)d_ws;
  float* wsf = (float*)d_ws;
  int* deg    = wsi + W_DEG;
  int* cur    = wsi + W_CUR;
  int* offs   = wsi + W_OFF;
  int* bsum   = wsi + W_BSUM;
  int* gstart = wsi + W_GSTART;
  int* eidb   = wsi + W_EID;
  float* gsum1 = wsf + W_GSUM1; float* gsq1 = wsf + W_GSQ1;
  float* gsum2 = wsf + W_GSUM2; float* gsq2 = wsf + W_GSQ2;
  float* scores_ = wsf + W_SCORES;
  float* A = wsf + W_A;   // src -> agg -> nnew -> x1 -> t -> x2
  float* B = wsf + W_B;   // dst -> g
  float* C = wsf + W_C;   // val -> n1
  float* wgc_ = wsf + W_WGC;

  float* outE = out + (size_t)NN_ * DIM;
  float* outC = out + (size_t)NN_ * DIM + (size_t)NE_ * EOUTF;

  zero_kernel<<<(W_ZEND + 255) / 256, 256, 0, stream>>>(wsi, W_ZEND);
  gstart_kernel<<<1, 128, 0, stream>>>(batch, gstart);
  prep_wg_kernel<<<128, 256, 0, stream>>>(Wg, wgc_);
  // A=src, B=dst, C=val
  proj_kernel<<<(NN_ + 31) / 32, 256, 0, stream>>>(node, Ws, bs, Wd, bd, Wv, bv,
                                                   A, B, C);
  edge_kernel<<<NE_ / 32, 256, 0, stream>>>(edgef, coords, EI, We1, be1, We2, be2,
                                            Wue, bue, A, B, scores_, deg, outE);
  scanA_kernel<<<(NN_ + 255) / 256, 256, 0, stream>>>(deg, offs, bsum);
  scanB_kernel<<<1, 128, 0, stream>>>(bsum);
  scanC_kernel<<<(NN_ + 255) / 256, 256, 0, stream>>>(offs, bsum);
  fill_kernel<<<(NE_ + 255) / 256, 256, 0, stream>>>(EI, offs, cur, eidb);
  // A := agg (src dead)
  agg_kernel<<<NN_ / 4, 256, 0, stream>>>(C, scores_, offs, eidb, EI, A);
  // A := node_new = agg @ Wun + bun (in-place, tile staged to LDS first)
  gemm128_kernel<<<(NN_ + 31) / 32, 256, 0, stream>>>(A, Wun, bun, A, 0);
  // B := g, A := x1 = g*nn + node (in-place)
  gate_kernel<<<(NN_ + 31) / 32, 256, 0, stream>>>(A, node, wgc_, bg, B, A);
  gn_stats_kernel<<<dim3(NG, 8), 256, 0, stream>>>(A, gstart, gsum1, gsq1);
  // C := n1 (val dead)
  gn_apply_kernel<<<(NN_ * 32 + 255) / 256, 256, 0, stream>>>(
      A, batch, gstart, gsum1, gsq1, g1w, g1b, g1a, C);
  // A := t = leaky(n1 @ Wf1 + bf1) (x1 dead)
  gemm128_kernel<<<(NN_ + 31) / 32, 256, 0, stream>>>(C, Wf1, bf1, A, 1);
  // A := x2 = g * (t @ Wf2 + bf2) + n1 (in-place)
  fx2_kernel<<<(NN_ + 31) / 32, 256, 0, stream>>>(A, Wf2, bf2, B, C, A);
  gn_stats_kernel<<<dim3(NG, 8), 256, 0, stream>>>(A, gstart, gsum2, gsq2);
  gn_apply_kernel<<<(NN_ * 32 + 255) / 256, 256, 0, stream>>>(
      A, batch, gstart, gsum2, gsq2, g2w, g2b, g2a, out);
  coords_kernel<<<(NN_ * 3 + 255) / 256, 256, 0, stream>>>(coords, outC);
}

// Round 6
// 828.864 us; speedup vs baseline: 1.1596x; 1.1596x over previous
//
#include <hip/hip_runtime.h>
#include <hip/hip_bf16.h>

#define NN_ 30000
#define NE_ 480000
#define DIM 128
#define EINF 16
#define EOUTF 16
#define NG 64
#define RSQRT_DH 0.17677669529663687f

typedef unsigned short u16;
typedef __attribute__((ext_vector_type(8))) short short8;
typedef __attribute__((ext_vector_type(4))) float floatx4;

// ---------------- workspace layout (32-bit word offsets) ----------------
#define W_DEG     0
#define W_CUR     30000
#define W_GSUM1   60000
#define W_GSQ1    68192
#define W_GSUM2   76384
#define W_GSQ2    84576
#define W_ZEND    92768
#define W_OFF     92768
#define W_BSUM    122772
#define W_GSTART  122900
#define W_EID     122968
#define W_SCORES  602968
#define W_A       2522968
#define W_B       6362968
#define W_C       10202968
#define W_WGC     14042968
#define W_WE2B    14075736
// end: 14,083,928 words = 56.34 MB

static __device__ __forceinline__ u16 f2bf(float x) {
  __hip_bfloat16 h = __float2bfloat16(x);
  return *reinterpret_cast<u16*>(&h);
}

// ---------------- GEMM building blocks (K=128, 32-row tile, 256 thr) ----
static __device__ __forceinline__ void stage32(const float* __restrict__ X,
                                               float* xsb, int row0, int tid) {
#pragma unroll
  for (int t = 0; t < 4; ++t) {
    int idx = tid + t * 256;
    int r = idx >> 5, c4 = (idx & 31) * 4;
    int row = row0 + r;
    float4 v; v.x = v.y = v.z = v.w = 0.f;
    if (row < NN_) v = *(const float4*)&X[(size_t)row * DIM + c4];
    *(float4*)&xsb[r * DIM + c4] = v;
  }
}

static __device__ __forceinline__ void mm_k128(const float* xsb, int ld,
                                               const float* __restrict__ W,
                                               float acc[4][4], int tid) {
  int cg = tid & 31, rg = tid >> 5;
  int c0 = cg * 4, r0 = rg * 4;
  for (int k = 0; k < 128; k += 4) {
    float4 w0 = *(const float4*)&W[(size_t)(k + 0) * DIM + c0];
    float4 w1 = *(const float4*)&W[(size_t)(k + 1) * DIM + c0];
    float4 w2 = *(const float4*)&W[(size_t)(k + 2) * DIM + c0];
    float4 w3 = *(const float4*)&W[(size_t)(k + 3) * DIM + c0];
#pragma unroll
    for (int u = 0; u < 4; ++u) {
      float4 xv = *(const float4*)&xsb[(r0 + u) * ld + k];
      acc[u][0] += xv.x * w0.x + xv.y * w1.x + xv.z * w2.x + xv.w * w3.x;
      acc[u][1] += xv.x * w0.y + xv.y * w1.y + xv.z * w2.y + xv.w * w3.y;
      acc[u][2] += xv.x * w0.z + xv.y * w1.z + xv.z * w2.z + xv.w * w3.z;
      acc[u][3] += xv.x * w0.w + xv.y * w1.w + xv.z * w2.w + xv.w * w3.w;
    }
  }
}

static __device__ __forceinline__ void epi_store(float acc[4][4],
    const float* __restrict__ bias, float* __restrict__ Y,
    int row0, int tid, int act) {
  int cg = tid & 31, rg = tid >> 5;
  int c0 = cg * 4, r0 = rg * 4;
  float4 bv = *(const float4*)&bias[c0];
#pragma unroll
  for (int u = 0; u < 4; ++u) {
    int row = row0 + r0 + u;
    if (row >= NN_) continue;
    float o0 = acc[u][0] + bv.x, o1 = acc[u][1] + bv.y;
    float o2 = acc[u][2] + bv.z, o3 = acc[u][3] + bv.w;
    if (act == 1) {
      o0 = o0 > 0.f ? o0 : 0.01f * o0;
      o1 = o1 > 0.f ? o1 : 0.01f * o1;
      o2 = o2 > 0.f ? o2 : 0.01f * o2;
      o3 = o3 > 0.f ? o3 : 0.01f * o3;
    }
    float4 ov; ov.x = o0; ov.y = o1; ov.z = o2; ov.w = o3;
    *(float4*)&Y[(size_t)row * DIM + c0] = ov;
  }
}

// ---------------- small utility kernels ----------------
__global__ void zero_kernel(int* p, int n) {
  int i = blockIdx.x * 256 + threadIdx.x;
  if (i < n) p[i] = 0;
}

__global__ void gstart_kernel(const int* __restrict__ batch, int* __restrict__ gstart) {
  int g = threadIdx.x;
  if (g > NG) return;
  int lo = 0, hi = NN_;
  while (lo < hi) { int mid = (lo + hi) >> 1; if (batch[mid] < g) lo = mid + 1; else hi = mid; }
  gstart[g] = lo;
}

__global__ void prep_wg_kernel(const float* __restrict__ Wg, float* __restrict__ Wgc) {
  int idx = blockIdx.x * 256 + threadIdx.x;  // 256*128
  int k = idx >> 7, c = idx & 127;
  float v;
  if (k < 128) v = Wg[(size_t)k * DIM + c] + Wg[(size_t)(256 + k) * DIM + c];
  else { int kk = k - 128; v = Wg[(size_t)(128 + kk) * DIM + c] - Wg[(size_t)(256 + kk) * DIM + c]; }
  Wgc[idx] = v;
}

// We2 -> bf16, fragment-linear B layout for mfma_f32_16x16x32_bf16:
// frag[(T*4+s)*64 + lane][j] = We2[s*32 + (lane>>4)*8 + j][T*16 + (lane&15)]
__global__ void prep_we2_kernel(const float* __restrict__ We2, u16* __restrict__ out) {
  int idx = blockIdx.x * 256 + threadIdx.x;   // 64 blocks -> 16384
  if (idx >= 16384) return;
  int j = idx & 7, lane = (idx >> 3) & 63, s = (idx >> 9) & 3, T = idx >> 11;
  int k = s * 32 + ((lane >> 4) << 3) + j;
  int n = T * 16 + (lane & 15);
  out[idx] = f2bf(We2[(size_t)k * DIM + n]);
}

// ---------------- node projections: src,dst,value ----------------
__global__ void __launch_bounds__(256) proj_kernel(
    const float* __restrict__ node,
    const float* __restrict__ Ws, const float* __restrict__ bs,
    const float* __restrict__ Wd, const float* __restrict__ bd,
    const float* __restrict__ Wv, const float* __restrict__ bv,
    float* __restrict__ srcp, float* __restrict__ dstp, float* __restrict__ valp) {
  __shared__ __align__(16) float xs[32 * DIM];
  int tid = threadIdx.x, row0 = blockIdx.x * 32;
  stage32(node, xs, row0, tid);
  __syncthreads();
  const float* Wt[3] = {Ws, Wd, Wv};
  const float* Bt[3] = {bs, bd, bv};
  float* Yt[3] = {srcp, dstp, valp};
#pragma unroll
  for (int w3 = 0; w3 < 3; ++w3) {
    float acc[4][4] = {};
    mm_k128(xs, DIM, Wt[w3], acc, tid);
    epi_store(acc, Bt[w3], Yt[w3], row0, tid, 0);
  }
}

// ---------------- generic node GEMM (in-place safe: own tile staged) ---
__global__ void __launch_bounds__(256) gemm128_kernel(
    const float* __restrict__ X, const float* __restrict__ W,
    const float* __restrict__ bias, float* __restrict__ Y, int act) {
  __shared__ __align__(16) float xs[32 * DIM];
  int tid = threadIdx.x, row0 = blockIdx.x * 32;
  stage32(X, xs, row0, tid);
  __syncthreads();
  float acc[4][4] = {};
  mm_k128(xs, DIM, W, acc, tid);
  epi_store(acc, bias, Y, row0, tid, act);
}

// ---------------- gate: g = sigmoid([nn,x,nn-x]@Wg+bg); x1 = g*nn + x ----
__global__ void __launch_bounds__(256) gate_kernel(
    const float* __restrict__ NNb, const float* __restrict__ NODE,
    const float* __restrict__ Wgc, const float* __restrict__ bg,
    float* __restrict__ G, float* __restrict__ X1) {
  __shared__ __align__(16) float xs0[32 * DIM];
  __shared__ __align__(16) float xs1[32 * DIM];
  int tid = threadIdx.x, row0 = blockIdx.x * 32;
  stage32(NNb, xs0, row0, tid);
  stage32(NODE, xs1, row0, tid);
  __syncthreads();
  float acc[4][4] = {};
  mm_k128(xs0, DIM, Wgc, acc, tid);
  mm_k128(xs1, DIM, Wgc + 128 * DIM, acc, tid);
  int cg = tid & 31, rg = tid >> 5, c0 = cg * 4, r0 = rg * 4;
  float4 bv = *(const float4*)&bg[c0];
#pragma unroll
  for (int u = 0; u < 4; ++u) {
    int row = row0 + r0 + u;
    if (row >= NN_) continue;
    float z0 = acc[u][0] + bv.x, z1 = acc[u][1] + bv.y;
    float z2 = acc[u][2] + bv.z, z3 = acc[u][3] + bv.w;
    float g0 = 1.f / (1.f + __expf(-z0));
    float g1 = 1.f / (1.f + __expf(-z1));
    float g2 = 1.f / (1.f + __expf(-z2));
    float g3 = 1.f / (1.f + __expf(-z3));
    float4 nn4 = *(const float4*)&xs0[(r0 + u) * DIM + c0];
    float4 nd4 = *(const float4*)&xs1[(r0 + u) * DIM + c0];
    float4 gv; gv.x = g0; gv.y = g1; gv.z = g2; gv.w = g3;
    float4 xv; xv.x = g0 * nn4.x + nd4.x; xv.y = g1 * nn4.y + nd4.y;
    xv.z = g2 * nn4.z + nd4.z; xv.w = g3 * nn4.w + nd4.w;
    *(float4*)&G[(size_t)row * DIM + c0] = gv;
    *(float4*)&X1[(size_t)row * DIM + c0] = xv;
  }
}

// ---------------- fx2 + residual gate epilogue: x2 = g*fx + n1 ----------
__global__ void __launch_bounds__(256) fx2_kernel(
    const float* __restrict__ T, const float* __restrict__ Wf2,
    const float* __restrict__ bf2, const float* __restrict__ G,
    const float* __restrict__ N1, float* __restrict__ X2) {
  __shared__ __align__(16) float xs[32 * DIM];
  int tid = threadIdx.x, row0 = blockIdx.x * 32;
  stage32(T, xs, row0, tid);
  __syncthreads();
  float acc[4][4] = {};
  mm_k128(xs, DIM, Wf2, acc, tid);
  int cg = tid & 31, rg = tid >> 5, c0 = cg * 4, r0 = rg * 4;
  float4 bv = *(const float4*)&bf2[c0];
#pragma unroll
  for (int u = 0; u < 4; ++u) {
    int row = row0 + r0 + u;
    if (row >= NN_) continue;
    float4 gv = *(const float4*)&G[(size_t)row * DIM + c0];
    float4 nv = *(const float4*)&N1[(size_t)row * DIM + c0];
    float4 ov;
    ov.x = gv.x * (acc[u][0] + bv.x) + nv.x;
    ov.y = gv.y * (acc[u][1] + bv.y) + nv.y;
    ov.z = gv.z * (acc[u][2] + bv.z) + nv.z;
    ov.w = gv.w * (acc[u][3] + bv.w) + nv.w;
    *(float4*)&X2[(size_t)row * DIM + c0] = ov;
  }
}

// ---------------- the big fused edge kernel (MFMA for h@We2) ------------
__global__ void __launch_bounds__(256) edge_kernel(
    const float* __restrict__ edgef, const float* __restrict__ coords,
    const int* __restrict__ EI,
    const float* __restrict__ We1, const float* __restrict__ be1,
    const float* __restrict__ be2, const u16* __restrict__ we2b,
    const float* __restrict__ Wue, const float* __restrict__ bue,
    const float* __restrict__ srcp, const float* __restrict__ dstp,
    float* __restrict__ scores, int* __restrict__ deg,
    float* __restrict__ outE) {
  __shared__ __align__(16) float xs[32 * 20];      // [32][20] padded edge inputs
  __shared__ __align__(16) float Wp[20 * DIM];     // padded We1
  __shared__ __align__(16) u16   hbf[32 * 136];    // h in bf16 (A-frag friendly)
  __shared__ __align__(16) float ers[32 * 132];    // er fp32 for Wue epilogue
  __shared__ __align__(16) float wue_s[DIM * EOUTF];
  __shared__ float bue_s[EOUTF];
  __shared__ int ii[32], jj[32];

  int tid = threadIdx.x;
  int e0 = blockIdx.x * 32;

  if (tid < 128) {                      // stage 32x16 edge feats as float4
    int r = tid >> 2, c4 = (tid & 3) * 4;
    *(float4*)&xs[r * 20 + c4] = *(const float4*)&edgef[(size_t)(e0 + r) * EINF + c4];
  }
  if (tid < 32) {
    int e = e0 + tid;
    int i = EI[e], j = EI[NE_ + e];
    ii[tid] = i; jj[tid] = j;
    float dx = coords[i * 3 + 0] - coords[j * 3 + 0];
    float dy = coords[i * 3 + 1] - coords[j * 3 + 1];
    float dz = coords[i * 3 + 2] - coords[j * 3 + 2];
    float dist = sqrtf(dx * dx + dy * dy + dz * dz + 1e-12f) * 0.1f;
    xs[tid * 20 + 16] = dist;
    xs[tid * 20 + 17] = 0.f; xs[tid * 20 + 18] = 0.f; xs[tid * 20 + 19] = 0.f;
    atomicAdd(&deg[i], 1);
  }
  for (int idx = tid; idx < 20 * DIM; idx += 256) {
    int k = idx >> 7, c = idx & 127;
    Wp[idx] = (k < 17) ? We1[(size_t)k * DIM + c] : 0.f;
  }
  for (int idx = tid; idx < DIM * EOUTF; idx += 256) wue_s[idx] = Wue[idx];
  if (tid < EOUTF) bue_s[tid] = bue[tid];
  __syncthreads();

  int cg = tid & 31, rg = tid >> 5, c0 = cg * 4, r0 = rg * 4;

  // h = leaky(x @ We1 + be1), K = 20 (padded), VALU; write bf16 to LDS
  {
    float acc[4][4] = {};
    for (int k = 0; k < 20; k += 4) {
      float4 w0 = *(const float4*)&Wp[(k + 0) * DIM + c0];
      float4 w1 = *(const float4*)&Wp[(k + 1) * DIM + c0];
      float4 w2 = *(const float4*)&Wp[(k + 2) * DIM + c0];
      float4 w3 = *(const float4*)&Wp[(k + 3) * DIM + c0];
#pragma unroll
      for (int u = 0; u < 4; ++u) {
        float4 xv = *(const float4*)&xs[(r0 + u) * 20 + k];
        acc[u][0] += xv.x * w0.x + xv.y * w1.x + xv.z * w2.x + xv.w * w3.x;
        acc[u][1] += xv.x * w0.y + xv.y * w1.y + xv.z * w2.y + xv.w * w3.y;
        acc[u][2] += xv.x * w0.z + xv.y * w1.z + xv.z * w2.z + xv.w * w3.z;
        acc[u][3] += xv.x * w0.w + xv.y * w1.w + xv.z * w2.w + xv.w * w3.w;
      }
    }
    float4 b1 = *(const float4*)&be1[c0];
#pragma unroll
    for (int u = 0; u < 4; ++u) {
      float h0 = acc[u][0] + b1.x, h1 = acc[u][1] + b1.y;
      float h2 = acc[u][2] + b1.z, h3 = acc[u][3] + b1.w;
      h0 = h0 > 0.f ? h0 : 0.01f * h0; h1 = h1 > 0.f ? h1 : 0.01f * h1;
      h2 = h2 > 0.f ? h2 : 0.01f * h2; h3 = h3 > 0.f ? h3 : 0.01f * h3;
      ushort4 pk; pk.x = f2bf(h0); pk.y = f2bf(h1); pk.z = f2bf(h2); pk.w = f2bf(h3);
      *(ushort4*)&hbf[(r0 + u) * 136 + c0] = pk;
    }
  }
  __syncthreads();

  // e2 = h @ We2 via MFMA. wave -> (mtile = w&1, nhalf = w>>1)
  int wv = tid >> 6, lane = tid & 63;
  int mtile = wv & 1, nhalf = wv >> 1;
  int quad = lane >> 4, lrow = lane & 15;
  int m0 = mtile * 16;

  short8 afrag[4];
#pragma unroll
  for (int s = 0; s < 4; ++s)
    afrag[s] = *(const short8*)&hbf[(m0 + lrow) * 136 + s * 32 + quad * 8];

  floatx4 dacc[4];
#pragma unroll
  for (int t = 0; t < 4; ++t) dacc[t] = (floatx4){0.f, 0.f, 0.f, 0.f};
#pragma unroll
  for (int s = 0; s < 4; ++s) {
#pragma unroll
    for (int t = 0; t < 4; ++t) {
      int T = nhalf * 4 + t;
      short8 bfrg = *(const short8*)&we2b[(size_t)((T * 4 + s) * 64 + lane) * 8];
      dacc[t] = __builtin_amdgcn_mfma_f32_16x16x32_bf16(afrag[s], bfrg, dacc[t], 0, 0, 0);
    }
  }

  // epilogue: er = dst_i * src_j * (e2 + be2) / sqrt(DH); |er| head sums
  float sh[2][4];
#pragma unroll
  for (int hh = 0; hh < 2; ++hh)
#pragma unroll
    for (int r = 0; r < 4; ++r) sh[hh][r] = 0.f;

#pragma unroll
  for (int t = 0; t < 4; ++t) {
    int col = nhalf * 64 + t * 16 + lrow;
    float b2v = be2[col];
#pragma unroll
    for (int r = 0; r < 4; ++r) {
      int erow = m0 + quad * 4 + r;
      float e2v = dacc[t][r] + b2v;
      float er = dstp[(size_t)ii[erow] * DIM + col] *
                 srcp[(size_t)jj[erow] * DIM + col] * e2v * RSQRT_DH;
      ers[erow * 132 + col] = er;
      sh[t >> 1][r] += fabsf(er);
    }
  }
#pragma unroll
  for (int m = 1; m < 16; m <<= 1) {
#pragma unroll
    for (int hh = 0; hh < 2; ++hh)
#pragma unroll
      for (int r = 0; r < 4; ++r) sh[hh][r] += __shfl_xor(sh[hh][r], m);
  }
  if (lrow == 0) {
#pragma unroll
    for (int r = 0; r < 4; ++r) {
      int erow = m0 + quad * 4 + r;
      scores[(size_t)(e0 + erow) * 4 + nhalf * 2 + 0] = sh[0][r];
      scores[(size_t)(e0 + erow) * 4 + nhalf * 2 + 1] = sh[1][r];
    }
  }
  __syncthreads();   // er fully in LDS

  // edge_new = er @ Wue + bue  -> f32 out
  int el = tid >> 3, oc2 = (tid & 7) * 2;
  float a0 = 0.f, a1 = 0.f;
  for (int k = 0; k < DIM; ++k) {
    float hv = ers[el * 132 + k];
    float2 wvv = *(const float2*)&wue_s[k * EOUTF + oc2];
    a0 += hv * wvv.x; a1 += hv * wvv.y;
  }
  size_t ob = (size_t)(e0 + el) * EOUTF + oc2;
  float2 o2; o2.x = a0 + bue_s[oc2]; o2.y = a1 + bue_s[oc2 + 1];
  *(float2*)&outE[ob] = o2;
}

// ---------------- CSR build ----------------
__global__ void scanA_kernel(const int* __restrict__ deg, int* __restrict__ off,
                             int* __restrict__ bsum) {
  __shared__ int buf[256];
  int tid = threadIdx.x;
  int i = blockIdx.x * 256 + tid;
  int v = (i < NN_) ? deg[i] : 0;
  buf[tid] = v;
  __syncthreads();
  for (int s = 1; s < 256; s <<= 1) {
    int t = (tid >= s) ? buf[tid - s] : 0;
    __syncthreads();
    buf[tid] += t;
    __syncthreads();
  }
  if (i < NN_) off[i] = buf[tid] - v;
  if (tid == 255) bsum[blockIdx.x] = buf[255];
}

__global__ void scanB_kernel(int* __restrict__ bsum) {
  const int NBLK = (NN_ + 255) / 256;
  __shared__ int buf[128];
  int tid = threadIdx.x;
  int v = (tid < NBLK) ? bsum[tid] : 0;
  buf[tid] = v;
  __syncthreads();
  for (int s = 1; s < 128; s <<= 1) {
    int t = (tid >= s) ? buf[tid - s] : 0;
    __syncthreads();
    buf[tid] += t;
    __syncthreads();
  }
  if (tid < NBLK) bsum[tid] = buf[tid] - v;
}

__global__ void scanC_kernel(int* __restrict__ off, const int* __restrict__ bsum) {
  int i = blockIdx.x * 256 + threadIdx.x;
  if (i < NN_) off[i] += bsum[i >> 8];
  if (i == 0) off[NN_] = NE_;
}

__global__ void fill_kernel(const int* __restrict__ EI, const int* __restrict__ off,
                            int* __restrict__ cur, int* __restrict__ eidb) {
  int e = blockIdx.x * 256 + threadIdx.x;
  if (e >= NE_) return;
  int i = EI[e];
  int p = atomicAdd(&cur[i], 1);
  eidb[off[i] + p] = e;
}

// ---------------- per-node softmax + aggregation (gather, no atomics) ---
__global__ void __launch_bounds__(256) agg_kernel(
    const float* __restrict__ valp, const float* __restrict__ scores,
    const int* __restrict__ off, const int* __restrict__ eidb,
    const int* __restrict__ EI, float* __restrict__ agg) {
  int n = blockIdx.x * 4 + (threadIdx.x >> 6);
  int lane = threadIdx.x & 63;
  if (n >= NN_) return;
  int s = off[n], e_end = off[n + 1];

  float m0 = -1e30f, m1 = -1e30f, m2 = -1e30f, m3 = -1e30f;
  for (int p = s + lane; p < e_end; p += 64) {
    int e = eidb[p];
    float4 sc = *(const float4*)&scores[(size_t)e * 4];
    m0 = fmaxf(m0, sc.x); m1 = fmaxf(m1, sc.y);
    m2 = fmaxf(m2, sc.z); m3 = fmaxf(m3, sc.w);
  }
#pragma unroll
  for (int d = 1; d < 64; d <<= 1) {
    m0 = fmaxf(m0, __shfl_xor(m0, d)); m1 = fmaxf(m1, __shfl_xor(m1, d));
    m2 = fmaxf(m2, __shfl_xor(m2, d)); m3 = fmaxf(m3, __shfl_xor(m3, d));
  }
  int h0 = lane >> 5;
  float mh0 = h0 ? m1 : m0;
  float mh1 = h0 ? m3 : m2;

  float acc0 = 0.f, acc1 = 0.f, den0 = 0.f, den1 = 0.f;
  for (int p = s; p < e_end; ++p) {
    int e = eidb[p];
    int j = EI[NE_ + e];
    float s0 = scores[(size_t)e * 4 + h0];
    float s1 = scores[(size_t)e * 4 + 2 + h0];
    float ex0 = __expf(s0 - mh0), ex1 = __expf(s1 - mh1);
    den0 += ex0; den1 += ex1;
    acc0 += ex0 * valp[(size_t)j * DIM + lane];
    acc1 += ex1 * valp[(size_t)j * DIM + 64 + lane];
  }
  if (e_end > s) {
    agg[(size_t)n * DIM + lane]      = acc0 / den0;
    agg[(size_t)n * DIM + 64 + lane] = acc1 / den1;
  } else {
    agg[(size_t)n * DIM + lane] = 0.f;
    agg[(size_t)n * DIM + 64 + lane] = 0.f;
  }
}

// ---------------- GraphNorm ----------------
__global__ void gn_stats_kernel(const float* __restrict__ X, const int* __restrict__ gstart,
                                float* __restrict__ gsum, float* __restrict__ gsq) {
  int g = blockIdx.x, slice = blockIdx.y;
  int s = gstart[g], e = gstart[g + 1];
  int c = threadIdx.x & 127, half = threadIdx.x >> 7;
  float sm = 0.f, sq = 0.f;
  for (int n = s + slice * 2 + half; n < e; n += 16) {
    float v = X[(size_t)n * DIM + c];
    sm += v; sq += v * v;
  }
  __shared__ float bsm[2][DIM], bsq[2][DIM];
  bsm[half][c] = sm; bsq[half][c] = sq;
  __syncthreads();
  if (half == 0) {
    atomicAdd(&gsum[g * DIM + c], bsm[0][c] + bsm[1][c]);
    atomicAdd(&gsq[g * DIM + c],  bsq[0][c] + bsq[1][c]);
  }
}

__global__ void gn_apply_kernel(const float* __restrict__ X, const int* __restrict__ batch,
    const int* __restrict__ gstart, const float* __restrict__ gsum,
    const float* __restrict__ gsq, const float* __restrict__ w,
    const float* __restrict__ b, const float* __restrict__ a,
    float* __restrict__ Y) {
  int idx = blockIdx.x * 256 + threadIdx.x;
  if (idx >= NN_ * 32) return;
  int n = idx >> 5, c4 = (idx & 31) * 4;
  int g = batch[n];
  float cnt = fmaxf((float)(gstart[g + 1] - gstart[g]), 1.f);
  float inv = 1.f / cnt;
  float4 xv = *(const float4*)&X[(size_t)n * DIM + c4];
  float4 sm = *(const float4*)&gsum[g * DIM + c4];
  float4 sq = *(const float4*)&gsq[g * DIM + c4];
  float4 av = *(const float4*)&a[c4];
  float4 wv = *(const float4*)&w[c4];
  float4 bv = *(const float4*)&b[c4];
  float4 ov;
  {
    float mean = sm.x * inv, msq = sq.x * inv, am = av.x * mean;
    float var = msq - 2.f * am * mean + am * am;
    ov.x = wv.x * (xv.x - am) * rsqrtf(var + 1e-5f) + bv.x;
  }
  {
    float mean = sm.y * inv, msq = sq.y * inv, am = av.y * mean;
    float var = msq - 2.f * am * mean + am * am;
    ov.y = wv.y * (xv.y - am) * rsqrtf(var + 1e-5f) + bv.y;
  }
  {
    float mean = sm.z * inv, msq = sq.z * inv, am = av.z * mean;
    float var = msq - 2.f * am * mean + am * am;
    ov.z = wv.z * (xv.z - am) * rsqrtf(var + 1e-5f) + bv.z;
  }
  {
    float mean = sm.w * inv, msq = sq.w * inv, am = av.w * mean;
    float var = msq - 2.f * am * mean + am * am;
    ov.w = wv.w * (xv.w - am) * rsqrtf(var + 1e-5f) + bv.w;
  }
  *(float4*)&Y[(size_t)n * DIM + c4] = ov;
}

__global__ void coords_kernel(const float* __restrict__ C, float* __restrict__ O) {
  int i = blockIdx.x * 256 + threadIdx.x;
  if (i < NN_ * 3) O[i] = C[i];
}

// ---------------- launcher ----------------
extern "C" void kernel_launch(void* const* d_in, const int* in_sizes, int n_in,
                              void* d_out, int out_size, void* d_ws, size_t ws_size,
                              hipStream_t stream) {
  (void)in_sizes; (void)n_in; (void)out_size; (void)ws_size;
  const float* node  = (const float*)d_in[0];
  const float* edgef = (const float*)d_in[1];
  const float* coords= (const float*)d_in[2];
  const float* Ws  = (const float*)d_in[3];  const float* bs  = (const float*)d_in[4];
  const float* Wd  = (const float*)d_in[5];  const float* bd  = (const float*)d_in[6];
  const float* Wv  = (const float*)d_in[7];  const float* bv  = (const float*)d_in[8];
  const float* We1 = (const float*)d_in[9];  const float* be1 = (const float*)d_in[10];
  const float* We2 = (const float*)d_in[11]; const float* be2 = (const float*)d_in[12];
  const float* Wun = (const float*)d_in[13]; const float* bun = (const float*)d_in[14];
  const float* Wue = (const float*)d_in[15]; const float* bue = (const float*)d_in[16];
  const float* Wg  = (const float*)d_in[17]; const float* bg  = (const float*)d_in[18];
  const float* Wf1 = (const float*)d_in[19]; const float* bf1 = (const float*)d_in[20];
  const float* Wf2 = (const float*)d_in[21]; const float* bf2 = (const float*)d_in[22];
  const float* g1w = (const float*)d_in[23]; const float* g1b = (const float*)d_in[24];
  const float* g1a = (const float*)d_in[25];
  const float* g2w = (const float*)d_in[26]; const float* g2b = (const float*)d_in[27];
  const float* g2a = (const float*)d_in[28];
  const int* EI    = (const int*)d_in[29];
  const int* batch = (const int*)d_in[30];
  float* out = (float*)d_out;

  int*   wsi = (int*)d_ws;
  float* wsf = (float*)d_ws;
  int* deg    = wsi + W_DEG;
  int* cur    = wsi + W_CUR;
  int* offs   = wsi + W_OFF;
  int* bsum   = wsi + W_BSUM;
  int* gstart = wsi + W_GSTART;
  int* eidb   = wsi + W_EID;
  float* gsum1 = wsf + W_GSUM1; float* gsq1 = wsf + W_GSQ1;
  float* gsum2 = wsf + W_GSUM2; float* gsq2 = wsf + W_GSQ2;
  float* scores_ = wsf + W_SCORES;
  float* A = wsf + W_A;   // src -> agg -> nnew -> x1 -> t -> x2
  float* B = wsf + W_B;   // dst -> g
  float* C = wsf + W_C;   // val -> n1
  float* wgc_ = wsf + W_WGC;
  u16*   we2b = (u16*)(wsf + W_WE2B);

  float* outE = out + (size_t)NN_ * DIM;
  float* outC = out + (size_t)NN_ * DIM + (size_t)NE_ * EOUTF;

  zero_kernel<<<(W_ZEND + 255) / 256, 256, 0, stream>>>(wsi, W_ZEND);
  gstart_kernel<<<1, 128, 0, stream>>>(batch, gstart);
  prep_wg_kernel<<<128, 256, 0, stream>>>(Wg, wgc_);
  prep_we2_kernel<<<64, 256, 0, stream>>>(We2, we2b);
  // A=src, B=dst, C=val
  proj_kernel<<<(NN_ + 31) / 32, 256, 0, stream>>>(node, Ws, bs, Wd, bd, Wv, bv,
                                                   A, B, C);
  edge_kernel<<<NE_ / 32, 256, 0, stream>>>(edgef, coords, EI, We1, be1,
                                            be2, we2b, Wue, bue,
                                            A, B, scores_, deg, outE);
  scanA_kernel<<<(NN_ + 255) / 256, 256, 0, stream>>>(deg, offs, bsum);
  scanB_kernel<<<1, 128, 0, stream>>>(bsum);
  scanC_kernel<<<(NN_ + 255) / 256, 256, 0, stream>>>(offs, bsum);
  fill_kernel<<<(NE_ + 255) / 256, 256, 0, stream>>>(EI, offs, cur, eidb);
  // A := agg (src dead)
  agg_kernel<<<NN_ / 4, 256, 0, stream>>>(C, scores_, offs, eidb, EI, A);
  // A := node_new = agg @ Wun + bun (in-place, tile staged to LDS first)
  gemm128_kernel<<<(NN_ + 31) / 32, 256, 0, stream>>>(A, Wun, bun, A, 0);
  // B := g, A := x1 = g*nn + node (in-place)
  gate_kernel<<<(NN_ + 31) / 32, 256, 0, stream>>>(A, node, wgc_, bg, B, A);
  gn_stats_kernel<<<dim3(NG, 8), 256, 0, stream>>>(A, gstart, gsum1, gsq1);
  // C := n1 (val dead)
  gn_apply_kernel<<<(NN_ * 32 + 255) / 256, 256, 0, stream>>>(
      A, batch, gstart, gsum1, gsq1, g1w, g1b, g1a, C);
  // A := t = leaky(n1 @ Wf1 + bf1) (x1 dead)
  gemm128_kernel<<<(NN_ + 31) / 32, 256, 0, stream>>>(C, Wf1, bf1, A, 1);
  // A := x2 = g * (t @ Wf2 + bf2) + n1 (in-place)
  fx2_kernel<<<(NN_ + 31) / 32, 256, 0, stream>>>(A, Wf2, bf2, B, C, A);
  gn_stats_kernel<<<dim3(NG, 8), 256, 0, stream>>>(A, gstart, gsum2, gsq2);
  gn_apply_kernel<<<(NN_ * 32 + 255) / 256, 256, 0, stream>>>(
      A, batch, gstart, gsum2, gsq2, g2w, g2b, g2a, out);
  coords_kernel<<<(NN_ * 3 + 255) / 256, 256, 0, stream>>>(coords, outC);
}

// Round 7
// 778.110 us; speedup vs baseline: 1.2352x; 1.0652x over previous
//
#include <hip/hip_runtime.h>
#include <hip/hip_bf16.h>

#define NN_ 30000
#define NE_ 480000
#define DIM 128
#define EINF 16
#define EOUTF 16
#define NG 64
#define RSQRT_DH 0.17677669529663687f

typedef unsigned short u16;
typedef __attribute__((ext_vector_type(8))) short short8;
typedef __attribute__((ext_vector_type(4))) float floatx4;

// ---------------- workspace layout (32-bit word offsets) ----------------
// end: 20,323,928 words = 81.3 MB (133 MB was proven safe in R1/R2)
#define W_DEG     0
#define W_CUR     30000
#define W_GSUM1   60000
#define W_GSQ1    68192
#define W_GSUM2   76384
#define W_GSQ2    84576
#define W_ZEND    92768
#define W_OFF     92768
#define W_BSUM    122772
#define W_GSTART  122900
#define W_EID     122968
#define W_JC      602968
#define W_SCORES  1082968
#define W_SRCB    3002968
#define W_DSTB    4922968
#define W_VALB    6842968
#define W_A       8762968
#define W_B       12602968
#define W_C       16442968
#define W_WGC     20282968
#define W_WE2B    20315736

static __device__ __forceinline__ u16 f2bf(float x) {
  __hip_bfloat16 h = __float2bfloat16(x);
  return *reinterpret_cast<u16*>(&h);
}
static __device__ __forceinline__ float bf2f(u16 v) {
  unsigned int b = ((unsigned int)v) << 16;
  return __uint_as_float(b);
}

// ---------------- GEMM building blocks (K=128, 32-row tile, 256 thr) ----
static __device__ __forceinline__ void stage32(const float* __restrict__ X,
                                               float* xsb, int row0, int tid) {
#pragma unroll
  for (int t = 0; t < 4; ++t) {
    int idx = tid + t * 256;
    int r = idx >> 5, c4 = (idx & 31) * 4;
    int row = row0 + r;
    float4 v; v.x = v.y = v.z = v.w = 0.f;
    if (row < NN_) v = *(const float4*)&X[(size_t)row * DIM + c4];
    *(float4*)&xsb[r * DIM + c4] = v;
  }
}

static __device__ __forceinline__ void mm_k128(const float* xsb, int ld,
                                               const float* __restrict__ W,
                                               float acc[4][4], int tid) {
  int cg = tid & 31, rg = tid >> 5;
  int c0 = cg * 4, r0 = rg * 4;
  for (int k = 0; k < 128; k += 4) {
    float4 w0 = *(const float4*)&W[(size_t)(k + 0) * DIM + c0];
    float4 w1 = *(const float4*)&W[(size_t)(k + 1) * DIM + c0];
    float4 w2 = *(const float4*)&W[(size_t)(k + 2) * DIM + c0];
    float4 w3 = *(const float4*)&W[(size_t)(k + 3) * DIM + c0];
#pragma unroll
    for (int u = 0; u < 4; ++u) {
      float4 xv = *(const float4*)&xsb[(r0 + u) * ld + k];
      acc[u][0] += xv.x * w0.x + xv.y * w1.x + xv.z * w2.x + xv.w * w3.x;
      acc[u][1] += xv.x * w0.y + xv.y * w1.y + xv.z * w2.y + xv.w * w3.y;
      acc[u][2] += xv.x * w0.z + xv.y * w1.z + xv.z * w2.z + xv.w * w3.z;
      acc[u][3] += xv.x * w0.w + xv.y * w1.w + xv.z * w2.w + xv.w * w3.w;
    }
  }
}

static __device__ __forceinline__ void epi_store(float acc[4][4],
    const float* __restrict__ bias, float* __restrict__ Y,
    int row0, int tid, int act) {
  int cg = tid & 31, rg = tid >> 5;
  int c0 = cg * 4, r0 = rg * 4;
  float4 bv = *(const float4*)&bias[c0];
#pragma unroll
  for (int u = 0; u < 4; ++u) {
    int row = row0 + r0 + u;
    if (row >= NN_) continue;
    float o0 = acc[u][0] + bv.x, o1 = acc[u][1] + bv.y;
    float o2 = acc[u][2] + bv.z, o3 = acc[u][3] + bv.w;
    if (act == 1) {
      o0 = o0 > 0.f ? o0 : 0.01f * o0;
      o1 = o1 > 0.f ? o1 : 0.01f * o1;
      o2 = o2 > 0.f ? o2 : 0.01f * o2;
      o3 = o3 > 0.f ? o3 : 0.01f * o3;
    }
    float4 ov; ov.x = o0; ov.y = o1; ov.z = o2; ov.w = o3;
    *(float4*)&Y[(size_t)row * DIM + c0] = ov;
  }
}

// bf16 variant for the projection outputs
static __device__ __forceinline__ void epi_store_bf(float acc[4][4],
    const float* __restrict__ bias, u16* __restrict__ Y,
    int row0, int tid) {
  int cg = tid & 31, rg = tid >> 5;
  int c0 = cg * 4, r0 = rg * 4;
  float4 bv = *(const float4*)&bias[c0];
#pragma unroll
  for (int u = 0; u < 4; ++u) {
    int row = row0 + r0 + u;
    if (row >= NN_) continue;
    ushort4 pk;
    pk.x = f2bf(acc[u][0] + bv.x); pk.y = f2bf(acc[u][1] + bv.y);
    pk.z = f2bf(acc[u][2] + bv.z); pk.w = f2bf(acc[u][3] + bv.w);
    *(ushort4*)&Y[(size_t)row * DIM + c0] = pk;
  }
}

// ---------------- small utility kernels ----------------
__global__ void zero_kernel(int* p, int n) {
  int i = blockIdx.x * 256 + threadIdx.x;
  if (i < n) p[i] = 0;
}

__global__ void gstart_kernel(const int* __restrict__ batch, int* __restrict__ gstart) {
  int g = threadIdx.x;
  if (g > NG) return;
  int lo = 0, hi = NN_;
  while (lo < hi) { int mid = (lo + hi) >> 1; if (batch[mid] < g) lo = mid + 1; else hi = mid; }
  gstart[g] = lo;
}

__global__ void prep_wg_kernel(const float* __restrict__ Wg, float* __restrict__ Wgc) {
  int idx = blockIdx.x * 256 + threadIdx.x;  // 256*128
  int k = idx >> 7, c = idx & 127;
  float v;
  if (k < 128) v = Wg[(size_t)k * DIM + c] + Wg[(size_t)(256 + k) * DIM + c];
  else { int kk = k - 128; v = Wg[(size_t)(128 + kk) * DIM + c] - Wg[(size_t)(256 + kk) * DIM + c]; }
  Wgc[idx] = v;
}

// We2 -> bf16, fragment-linear B layout for mfma_f32_16x16x32_bf16
__global__ void prep_we2_kernel(const float* __restrict__ We2, u16* __restrict__ out) {
  int idx = blockIdx.x * 256 + threadIdx.x;   // 64 blocks -> 16384
  if (idx >= 16384) return;
  int j = idx & 7, lane = (idx >> 3) & 63, s = (idx >> 9) & 3, T = idx >> 11;
  int k = s * 32 + ((lane >> 4) << 3) + j;
  int n = T * 16 + (lane & 15);
  out[idx] = f2bf(We2[(size_t)k * DIM + n]);
}

__global__ void deg_kernel(const int* __restrict__ EI, int* __restrict__ deg) {
  int e = blockIdx.x * 256 + threadIdx.x;
  if (e < NE_) atomicAdd(&deg[EI[e]], 1);
}

// ---------------- node projections: src,dst,value (bf16 outputs) -------
__global__ void __launch_bounds__(256) proj_kernel(
    const float* __restrict__ node,
    const float* __restrict__ Ws, const float* __restrict__ bs,
    const float* __restrict__ Wd, const float* __restrict__ bd,
    const float* __restrict__ Wv, const float* __restrict__ bv,
    u16* __restrict__ srcb, u16* __restrict__ dstb, u16* __restrict__ valb) {
  __shared__ __align__(16) float xs[32 * DIM];
  int tid = threadIdx.x, row0 = blockIdx.x * 32;
  stage32(node, xs, row0, tid);
  __syncthreads();
  const float* Wt[3] = {Ws, Wd, Wv};
  const float* Bt[3] = {bs, bd, bv};
  u16* Yt[3] = {srcb, dstb, valb};
#pragma unroll
  for (int w3 = 0; w3 < 3; ++w3) {
    float acc[4][4] = {};
    mm_k128(xs, DIM, Wt[w3], acc, tid);
    epi_store_bf(acc, Bt[w3], Yt[w3], row0, tid);
  }
}

// ---------------- generic node GEMM (in-place safe) --------------------
__global__ void __launch_bounds__(256) gemm128_kernel(
    const float* __restrict__ X, const float* __restrict__ W,
    const float* __restrict__ bias, float* __restrict__ Y, int act) {
  __shared__ __align__(16) float xs[32 * DIM];
  int tid = threadIdx.x, row0 = blockIdx.x * 32;
  stage32(X, xs, row0, tid);
  __syncthreads();
  float acc[4][4] = {};
  mm_k128(xs, DIM, W, acc, tid);
  epi_store(acc, bias, Y, row0, tid, act);
}

// ---------------- gate ----------------
__global__ void __launch_bounds__(256) gate_kernel(
    const float* __restrict__ NNb, const float* __restrict__ NODE,
    const float* __restrict__ Wgc, const float* __restrict__ bg,
    float* __restrict__ G, float* __restrict__ X1) {
  __shared__ __align__(16) float xs0[32 * DIM];
  __shared__ __align__(16) float xs1[32 * DIM];
  int tid = threadIdx.x, row0 = blockIdx.x * 32;
  stage32(NNb, xs0, row0, tid);
  stage32(NODE, xs1, row0, tid);
  __syncthreads();
  float acc[4][4] = {};
  mm_k128(xs0, DIM, Wgc, acc, tid);
  mm_k128(xs1, DIM, Wgc + 128 * DIM, acc, tid);
  int cg = tid & 31, rg = tid >> 5, c0 = cg * 4, r0 = rg * 4;
  float4 bv = *(const float4*)&bg[c0];
#pragma unroll
  for (int u = 0; u < 4; ++u) {
    int row = row0 + r0 + u;
    if (row >= NN_) continue;
    float z0 = acc[u][0] + bv.x, z1 = acc[u][1] + bv.y;
    float z2 = acc[u][2] + bv.z, z3 = acc[u][3] + bv.w;
    float g0 = 1.f / (1.f + __expf(-z0));
    float g1 = 1.f / (1.f + __expf(-z1));
    float g2 = 1.f / (1.f + __expf(-z2));
    float g3 = 1.f / (1.f + __expf(-z3));
    float4 nn4 = *(const float4*)&xs0[(r0 + u) * DIM + c0];
    float4 nd4 = *(const float4*)&xs1[(r0 + u) * DIM + c0];
    float4 gv; gv.x = g0; gv.y = g1; gv.z = g2; gv.w = g3;
    float4 xv; xv.x = g0 * nn4.x + nd4.x; xv.y = g1 * nn4.y + nd4.y;
    xv.z = g2 * nn4.z + nd4.z; xv.w = g3 * nn4.w + nd4.w;
    *(float4*)&G[(size_t)row * DIM + c0] = gv;
    *(float4*)&X1[(size_t)row * DIM + c0] = xv;
  }
}

// ---------------- fx2 ----------------
__global__ void __launch_bounds__(256) fx2_kernel(
    const float* __restrict__ T, const float* __restrict__ Wf2,
    const float* __restrict__ bf2, const float* __restrict__ G,
    const float* __restrict__ N1, float* __restrict__ X2) {
  __shared__ __align__(16) float xs[32 * DIM];
  int tid = threadIdx.x, row0 = blockIdx.x * 32;
  stage32(T, xs, row0, tid);
  __syncthreads();
  float acc[4][4] = {};
  mm_k128(xs, DIM, Wf2, acc, tid);
  int cg = tid & 31, rg = tid >> 5, c0 = cg * 4, r0 = rg * 4;
  float4 bv = *(const float4*)&bf2[c0];
#pragma unroll
  for (int u = 0; u < 4; ++u) {
    int row = row0 + r0 + u;
    if (row >= NN_) continue;
    float4 gv = *(const float4*)&G[(size_t)row * DIM + c0];
    float4 nv = *(const float4*)&N1[(size_t)row * DIM + c0];
    float4 ov;
    ov.x = gv.x * (acc[u][0] + bv.x) + nv.x;
    ov.y = gv.y * (acc[u][1] + bv.y) + nv.y;
    ov.z = gv.z * (acc[u][2] + bv.z) + nv.z;
    ov.w = gv.w * (acc[u][3] + bv.w) + nv.w;
    *(float4*)&X2[(size_t)row * DIM + c0] = ov;
  }
}

// ---------------- CSR build ----------------
__global__ void scanA_kernel(const int* __restrict__ deg, int* __restrict__ off,
                             int* __restrict__ bsum) {
  __shared__ int buf[256];
  int tid = threadIdx.x;
  int i = blockIdx.x * 256 + tid;
  int v = (i < NN_) ? deg[i] : 0;
  buf[tid] = v;
  __syncthreads();
  for (int s = 1; s < 256; s <<= 1) {
    int t = (tid >= s) ? buf[tid - s] : 0;
    __syncthreads();
    buf[tid] += t;
    __syncthreads();
  }
  if (i < NN_) off[i] = buf[tid] - v;
  if (tid == 255) bsum[blockIdx.x] = buf[255];
}

__global__ void scanB_kernel(int* __restrict__ bsum) {
  const int NBLK = (NN_ + 255) / 256;
  __shared__ int buf[128];
  int tid = threadIdx.x;
  int v = (tid < NBLK) ? bsum[tid] : 0;
  buf[tid] = v;
  __syncthreads();
  for (int s = 1; s < 128; s <<= 1) {
    int t = (tid >= s) ? buf[tid - s] : 0;
    __syncthreads();
    buf[tid] += t;
    __syncthreads();
  }
  if (tid < NBLK) bsum[tid] = buf[tid] - v;
}

__global__ void scanC_kernel(int* __restrict__ off, const int* __restrict__ bsum) {
  int i = blockIdx.x * 256 + threadIdx.x;
  if (i < NN_) off[i] += bsum[i >> 8];
  if (i == 0) off[NN_] = NE_;
}

__global__ void fill_kernel(const int* __restrict__ EI, const int* __restrict__ off,
                            int* __restrict__ cur, int* __restrict__ eidb,
                            int* __restrict__ jcsr) {
  int e = blockIdx.x * 256 + threadIdx.x;
  if (e >= NE_) return;
  int i = EI[e];
  int p = atomicAdd(&cur[i], 1);
  int pos = off[i] + p;
  eidb[pos] = e;
  jcsr[pos] = EI[NE_ + e];
}

// ---------------- fused edge kernel, CSR order ----------------
__global__ void __launch_bounds__(256) edge_kernel(
    const float* __restrict__ edgef, const float* __restrict__ coords,
    const int* __restrict__ EI, const int* __restrict__ eidb,
    const float* __restrict__ We1, const float* __restrict__ be1,
    const float* __restrict__ be2, const u16* __restrict__ we2b,
    const float* __restrict__ Wue, const float* __restrict__ bue,
    const u16* __restrict__ srcb, const u16* __restrict__ dstb,
    float* __restrict__ scores, float* __restrict__ outE) {
  __shared__ __align__(16) float xs[32 * 20];
  __shared__ __align__(16) float Wp[20 * DIM];
  __shared__ __align__(16) u16   hbf[32 * 136];
  __shared__ __align__(16) float ers[32 * 132];
  __shared__ __align__(16) float wue_t[16 * 132];   // transposed, padded
  __shared__ float bue_s[EOUTF];
  __shared__ int ii[32], jj[32], ee[32];

  int tid = threadIdx.x;
  int p0 = blockIdx.x * 32;

  if (tid < 32) {
    int p = p0 + tid;
    int e = eidb[p];
    ee[tid] = e;
    int i = EI[e], j = EI[NE_ + e];
    ii[tid] = i; jj[tid] = j;
    float dx = coords[i * 3 + 0] - coords[j * 3 + 0];
    float dy = coords[i * 3 + 1] - coords[j * 3 + 1];
    float dz = coords[i * 3 + 2] - coords[j * 3 + 2];
    float dist = sqrtf(dx * dx + dy * dy + dz * dz + 1e-12f) * 0.1f;
    xs[tid * 20 + 16] = dist;
    xs[tid * 20 + 17] = 0.f; xs[tid * 20 + 18] = 0.f; xs[tid * 20 + 19] = 0.f;
  }
  for (int idx = tid; idx < 20 * DIM; idx += 256) {
    int k = idx >> 7, c = idx & 127;
    Wp[idx] = (k < 17) ? We1[(size_t)k * DIM + c] : 0.f;
  }
  for (int idx = tid; idx < 16 * DIM; idx += 256) {
    int oc = idx >> 7, k = idx & 127;
    wue_t[oc * 132 + k] = Wue[(size_t)k * EOUTF + oc];
  }
  if (tid < EOUTF) bue_s[tid] = bue[tid];
  __syncthreads();

  if (tid < 128) {                      // stage 32x16 edge feats (gathered rows)
    int r = tid >> 2, c4 = (tid & 3) * 4;
    *(float4*)&xs[r * 20 + c4] = *(const float4*)&edgef[(size_t)ee[r] * EINF + c4];
  }
  __syncthreads();

  int cg = tid & 31, rg = tid >> 5, c0 = cg * 4, r0 = rg * 4;

  // h = leaky(x @ We1 + be1), K=20 (padded), VALU; write bf16 to LDS
  {
    float acc[4][4] = {};
    for (int k = 0; k < 20; k += 4) {
      float4 w0 = *(const float4*)&Wp[(k + 0) * DIM + c0];
      float4 w1 = *(const float4*)&Wp[(k + 1) * DIM + c0];
      float4 w2 = *(const float4*)&Wp[(k + 2) * DIM + c0];
      float4 w3 = *(const float4*)&Wp[(k + 3) * DIM + c0];
#pragma unroll
      for (int u = 0; u < 4; ++u) {
        float4 xv = *(const float4*)&xs[(r0 + u) * 20 + k];
        acc[u][0] += xv.x * w0.x + xv.y * w1.x + xv.z * w2.x + xv.w * w3.x;
        acc[u][1] += xv.x * w0.y + xv.y * w1.y + xv.z * w2.y + xv.w * w3.y;
        acc[u][2] += xv.x * w0.z + xv.y * w1.z + xv.z * w2.z + xv.w * w3.z;
        acc[u][3] += xv.x * w0.w + xv.y * w1.w + xv.z * w2.w + xv.w * w3.w;
      }
    }
    float4 b1 = *(const float4*)&be1[c0];
#pragma unroll
    for (int u = 0; u < 4; ++u) {
      float h0 = acc[u][0] + b1.x, h1 = acc[u][1] + b1.y;
      float h2 = acc[u][2] + b1.z, h3 = acc[u][3] + b1.w;
      h0 = h0 > 0.f ? h0 : 0.01f * h0; h1 = h1 > 0.f ? h1 : 0.01f * h1;
      h2 = h2 > 0.f ? h2 : 0.01f * h2; h3 = h3 > 0.f ? h3 : 0.01f * h3;
      ushort4 pk; pk.x = f2bf(h0); pk.y = f2bf(h1); pk.z = f2bf(h2); pk.w = f2bf(h3);
      *(ushort4*)&hbf[(r0 + u) * 136 + c0] = pk;
    }
  }
  __syncthreads();

  // e2 = h @ We2 via MFMA. wave -> (mtile = w&1, nhalf = w>>1)
  int wv = tid >> 6, lane = tid & 63;
  int mtile = wv & 1, nhalf = wv >> 1;
  int quad = lane >> 4, lrow = lane & 15;
  int m0 = mtile * 16;

  short8 afrag[4];
#pragma unroll
  for (int s = 0; s < 4; ++s)
    afrag[s] = *(const short8*)&hbf[(m0 + lrow) * 136 + s * 32 + quad * 8];

  floatx4 dacc[4];
#pragma unroll
  for (int t = 0; t < 4; ++t) dacc[t] = (floatx4){0.f, 0.f, 0.f, 0.f};
#pragma unroll
  for (int s = 0; s < 4; ++s) {
#pragma unroll
    for (int t = 0; t < 4; ++t) {
      int T = nhalf * 4 + t;
      short8 bfrg = *(const short8*)&we2b[(size_t)((T * 4 + s) * 64 + lane) * 8];
      dacc[t] = __builtin_amdgcn_mfma_f32_16x16x32_bf16(afrag[s], bfrg, dacc[t], 0, 0, 0);
    }
  }

  // epilogue: er = dst_i * src_j * (e2 + be2) / sqrt(DH); |er| head sums
  float sh[2][4];
#pragma unroll
  for (int hh = 0; hh < 2; ++hh)
#pragma unroll
    for (int r = 0; r < 4; ++r) sh[hh][r] = 0.f;

#pragma unroll
  for (int t = 0; t < 4; ++t) {
    int col = nhalf * 64 + t * 16 + lrow;
    float b2v = be2[col];
#pragma unroll
    for (int r = 0; r < 4; ++r) {
      int erow = m0 + quad * 4 + r;
      float e2v = dacc[t][r] + b2v;
      float dv = bf2f(dstb[(size_t)ii[erow] * DIM + col]);
      float sv = bf2f(srcb[(size_t)jj[erow] * DIM + col]);
      float er = dv * sv * e2v * RSQRT_DH;
      ers[erow * 132 + col] = er;
      sh[t >> 1][r] += fabsf(er);
    }
  }
#pragma unroll
  for (int m = 1; m < 16; m <<= 1) {
#pragma unroll
    for (int hh = 0; hh < 2; ++hh)
#pragma unroll
      for (int r = 0; r < 4; ++r) sh[hh][r] += __shfl_xor(sh[hh][r], m);
  }
  if (lrow == 0) {
#pragma unroll
    for (int r = 0; r < 4; ++r) {
      int erow = m0 + quad * 4 + r;
      scores[(size_t)(p0 + erow) * 4 + nhalf * 2 + 0] = sh[0][r];
      scores[(size_t)(p0 + erow) * 4 + nhalf * 2 + 1] = sh[1][r];
    }
  }
  __syncthreads();   // er fully in LDS

  // edge_new = er @ Wue + bue  -> scatter by original edge id
  int el = tid >> 3, oc2 = (tid & 7) * 2;
  float a0 = 0.f, a1 = 0.f;
  for (int k = 0; k < DIM; k += 4) {
    float4 e4 = *(const float4*)&ers[el * 132 + k];
    float4 w0 = *(const float4*)&wue_t[oc2 * 132 + k];
    float4 w1 = *(const float4*)&wue_t[(oc2 + 1) * 132 + k];
    a0 += e4.x * w0.x + e4.y * w0.y + e4.z * w0.z + e4.w * w0.w;
    a1 += e4.x * w1.x + e4.y * w1.y + e4.z * w1.z + e4.w * w1.w;
  }
  size_t ob = (size_t)ee[el] * EOUTF + oc2;
  float2 o2; o2.x = a0 + bue_s[oc2]; o2.y = a1 + bue_s[oc2 + 1];
  *(float2*)&outE[ob] = o2;
}

// ---------------- per-node softmax + aggregation (CSR gather) -----------
__global__ void __launch_bounds__(256) agg_kernel(
    const u16* __restrict__ valb, const float* __restrict__ scores,
    const int* __restrict__ off, const int* __restrict__ jcsr,
    float* __restrict__ agg) {
  int n = blockIdx.x * 4 + (threadIdx.x >> 6);
  int lane = threadIdx.x & 63;
  if (n >= NN_) return;
  int s = off[n], e_end = off[n + 1];

  float m0 = -1e30f, m1 = -1e30f, m2 = -1e30f, m3 = -1e30f;
  for (int p = s + lane; p < e_end; p += 64) {
    float4 sc = *(const float4*)&scores[(size_t)p * 4];
    m0 = fmaxf(m0, sc.x); m1 = fmaxf(m1, sc.y);
    m2 = fmaxf(m2, sc.z); m3 = fmaxf(m3, sc.w);
  }
#pragma unroll
  for (int d = 1; d < 64; d <<= 1) {
    m0 = fmaxf(m0, __shfl_xor(m0, d)); m1 = fmaxf(m1, __shfl_xor(m1, d));
    m2 = fmaxf(m2, __shfl_xor(m2, d)); m3 = fmaxf(m3, __shfl_xor(m3, d));
  }
  int h0 = lane >> 5;
  float mh0 = h0 ? m1 : m0;
  float mh1 = h0 ? m3 : m2;

  float acc0 = 0.f, acc1 = 0.f, den0 = 0.f, den1 = 0.f;
  for (int p = s; p < e_end; ++p) {
    int j = jcsr[p];
    float s0 = scores[(size_t)p * 4 + h0];
    float s1 = scores[(size_t)p * 4 + 2 + h0];
    float ex0 = __expf(s0 - mh0), ex1 = __expf(s1 - mh1);
    den0 += ex0; den1 += ex1;
    acc0 += ex0 * bf2f(valb[(size_t)j * DIM + lane]);
    acc1 += ex1 * bf2f(valb[(size_t)j * DIM + 64 + lane]);
  }
  if (e_end > s) {
    agg[(size_t)n * DIM + lane]      = acc0 / den0;
    agg[(size_t)n * DIM + 64 + lane] = acc1 / den1;
  } else {
    agg[(size_t)n * DIM + lane] = 0.f;
    agg[(size_t)n * DIM + 64 + lane] = 0.f;
  }
}

// ---------------- GraphNorm ----------------
__global__ void gn_stats_kernel(const float* __restrict__ X, const int* __restrict__ gstart,
                                float* __restrict__ gsum, float* __restrict__ gsq) {
  int g = blockIdx.x, slice = blockIdx.y;
  int s = gstart[g], e = gstart[g + 1];
  int c = threadIdx.x & 127, half = threadIdx.x >> 7;
  float sm = 0.f, sq = 0.f;
  for (int n = s + slice * 2 + half; n < e; n += 16) {
    float v = X[(size_t)n * DIM + c];
    sm += v; sq += v * v;
  }
  __shared__ float bsm[2][DIM], bsq[2][DIM];
  bsm[half][c] = sm; bsq[half][c] = sq;
  __syncthreads();
  if (half == 0) {
    atomicAdd(&gsum[g * DIM + c], bsm[0][c] + bsm[1][c]);
    atomicAdd(&gsq[g * DIM + c],  bsq[0][c] + bsq[1][c]);
  }
}

__global__ void gn_apply_kernel(const float* __restrict__ X, const int* __restrict__ batch,
    const int* __restrict__ gstart, const float* __restrict__ gsum,
    const float* __restrict__ gsq, const float* __restrict__ w,
    const float* __restrict__ b, const float* __restrict__ a,
    float* __restrict__ Y) {
  int idx = blockIdx.x * 256 + threadIdx.x;
  if (idx >= NN_ * 32) return;
  int n = idx >> 5, c4 = (idx & 31) * 4;
  int g = batch[n];
  float cnt = fmaxf((float)(gstart[g + 1] - gstart[g]), 1.f);
  float inv = 1.f / cnt;
  float4 xv = *(const float4*)&X[(size_t)n * DIM + c4];
  float4 sm = *(const float4*)&gsum[g * DIM + c4];
  float4 sq = *(const float4*)&gsq[g * DIM + c4];
  float4 av = *(const float4*)&a[c4];
  float4 wv = *(const float4*)&w[c4];
  float4 bv = *(const float4*)&b[c4];
  float4 ov;
  {
    float mean = sm.x * inv, msq = sq.x * inv, am = av.x * mean;
    float var = msq - 2.f * am * mean + am * am;
    ov.x = wv.x * (xv.x - am) * rsqrtf(var + 1e-5f) + bv.x;
  }
  {
    float mean = sm.y * inv, msq = sq.y * inv, am = av.y * mean;
    float var = msq - 2.f * am * mean + am * am;
    ov.y = wv.y * (xv.y - am) * rsqrtf(var + 1e-5f) + bv.y;
  }
  {
    float mean = sm.z * inv, msq = sq.z * inv, am = av.z * mean;
    float var = msq - 2.f * am * mean + am * am;
    ov.z = wv.z * (xv.z - am) * rsqrtf(var + 1e-5f) + bv.z;
  }
  {
    float mean = sm.w * inv, msq = sq.w * inv, am = av.w * mean;
    float var = msq - 2.f * am * mean + am * am;
    ov.w = wv.w * (xv.w - am) * rsqrtf(var + 1e-5f) + bv.w;
  }
  *(float4*)&Y[(size_t)n * DIM + c4] = ov;
}

__global__ void coords_kernel(const float* __restrict__ C, float* __restrict__ O) {
  int i = blockIdx.x * 256 + threadIdx.x;
  if (i < NN_ * 3) O[i] = C[i];
}

// ---------------- launcher ----------------
extern "C" void kernel_launch(void* const* d_in, const int* in_sizes, int n_in,
                              void* d_out, int out_size, void* d_ws, size_t ws_size,
                              hipStream_t stream) {
  (void)in_sizes; (void)n_in; (void)out_size; (void)ws_size;
  const float* node  = (const float*)d_in[0];
  const float* edgef = (const float*)d_in[1];
  const float* coords= (const float*)d_in[2];
  const float* Ws  = (const float*)d_in[3];  const float* bs  = (const float*)d_in[4];
  const float* Wd  = (const float*)d_in[5];  const float* bd  = (const float*)d_in[6];
  const float* Wv  = (const float*)d_in[7];  const float* bv  = (const float*)d_in[8];
  const float* We1 = (const float*)d_in[9];  const float* be1 = (const float*)d_in[10];
  const float* We2 = (const float*)d_in[11]; const float* be2 = (const float*)d_in[12];
  const float* Wun = (const float*)d_in[13]; const float* bun = (const float*)d_in[14];
  const float* Wue = (const float*)d_in[15]; const float* bue = (const float*)d_in[16];
  const float* Wg  = (const float*)d_in[17]; const float* bg  = (const float*)d_in[18];
  const float* Wf1 = (const float*)d_in[19]; const float* bf1 = (const float*)d_in[20];
  const float* Wf2 = (const float*)d_in[21]; const float* bf2 = (const float*)d_in[22];
  const float* g1w = (const float*)d_in[23]; const float* g1b = (const float*)d_in[24];
  const float* g1a = (const float*)d_in[25];
  const float* g2w = (const float*)d_in[26]; const float* g2b = (const float*)d_in[27];
  const float* g2a = (const float*)d_in[28];
  const int* EI    = (const int*)d_in[29];
  const int* batch = (const int*)d_in[30];
  float* out = (float*)d_out;

  int*   wsi = (int*)d_ws;
  float* wsf = (float*)d_ws;
  int* deg    = wsi + W_DEG;
  int* cur    = wsi + W_CUR;
  int* offs   = wsi + W_OFF;
  int* bsum   = wsi + W_BSUM;
  int* gstart = wsi + W_GSTART;
  int* eidb   = wsi + W_EID;
  int* jcsr   = wsi + W_JC;
  float* gsum1 = wsf + W_GSUM1; float* gsq1 = wsf + W_GSQ1;
  float* gsum2 = wsf + W_GSUM2; float* gsq2 = wsf + W_GSQ2;
  float* scores_ = wsf + W_SCORES;
  u16* srcb = (u16*)(wsf + W_SRCB);
  u16* dstb = (u16*)(wsf + W_DSTB);
  u16* valb = (u16*)(wsf + W_VALB);
  float* A = wsf + W_A;   // agg -> nnew -> x1 -> t -> x2
  float* B = wsf + W_B;   // g
  float* C = wsf + W_C;   // n1
  float* wgc_ = wsf + W_WGC;
  u16*   we2b = (u16*)(wsf + W_WE2B);

  float* outE = out + (size_t)NN_ * DIM;
  float* outC = out + (size_t)NN_ * DIM + (size_t)NE_ * EOUTF;

  zero_kernel<<<(W_ZEND + 255) / 256, 256, 0, stream>>>(wsi, W_ZEND);
  gstart_kernel<<<1, 128, 0, stream>>>(batch, gstart);
  prep_wg_kernel<<<128, 256, 0, stream>>>(Wg, wgc_);
  prep_we2_kernel<<<64, 256, 0, stream>>>(We2, we2b);
  // CSR build (independent of projections)
  deg_kernel<<<(NE_ + 255) / 256, 256, 0, stream>>>(EI, deg);
  scanA_kernel<<<(NN_ + 255) / 256, 256, 0, stream>>>(deg, offs, bsum);
  scanB_kernel<<<1, 128, 0, stream>>>(bsum);
  scanC_kernel<<<(NN_ + 255) / 256, 256, 0, stream>>>(offs, bsum);
  fill_kernel<<<(NE_ + 255) / 256, 256, 0, stream>>>(EI, offs, cur, eidb, jcsr);
  // projections (bf16)
  proj_kernel<<<(NN_ + 31) / 32, 256, 0, stream>>>(node, Ws, bs, Wd, bd, Wv, bv,
                                                   srcb, dstb, valb);
  // edge pipeline in CSR order
  edge_kernel<<<NE_ / 32, 256, 0, stream>>>(edgef, coords, EI, eidb, We1, be1,
                                            be2, we2b, Wue, bue,
                                            srcb, dstb, scores_, outE);
  // A := agg
  agg_kernel<<<NN_ / 4, 256, 0, stream>>>(valb, scores_, offs, jcsr, A);
  // A := node_new (in-place)
  gemm128_kernel<<<(NN_ + 31) / 32, 256, 0, stream>>>(A, Wun, bun, A, 0);
  // B := g, A := x1 (in-place)
  gate_kernel<<<(NN_ + 31) / 32, 256, 0, stream>>>(A, node, wgc_, bg, B, A);
  gn_stats_kernel<<<dim3(NG, 8), 256, 0, stream>>>(A, gstart, gsum1, gsq1);
  // C := n1
  gn_apply_kernel<<<(NN_ * 32 + 255) / 256, 256, 0, stream>>>(
      A, batch, gstart, gsum1, gsq1, g1w, g1b, g1a, C);
  // A := t = leaky(n1 @ Wf1 + bf1)
  gemm128_kernel<<<(NN_ + 31) / 32, 256, 0, stream>>>(C, Wf1, bf1, A, 1);
  // A := x2 = g*(t@Wf2+bf2) + n1 (in-place)
  fx2_kernel<<<(NN_ + 31) / 32, 256, 0, stream>>>(A, Wf2, bf2, B, C, A);
  gn_stats_kernel<<<dim3(NG, 8), 256, 0, stream>>>(A, gstart, gsum2, gsq2);
  gn_apply_kernel<<<(NN_ * 32 + 255) / 256, 256, 0, stream>>>(
      A, batch, gstart, gsum2, gsq2, g2w, g2b, g2a, out);
  coords_kernel<<<(NN_ * 3 + 255) / 256, 256, 0, stream>>>(coords, outC);
}